// Round 5
// baseline (269.093 us; speedup 1.0000x reference)
//
#include <hip/hip_runtime.h>
#include <cstdint>
#include <cstddef>

// ---------------- problem constants ----------------
#define B_ 4
#define S_ 4096
#define E_ 512
#define NPOS 16384      // B*S
#define QKVC 1536       // 3*E
#define K_ 512          // contraction dim of both GEMMs
#define MIDBLK 512      // mid_kernel grid size (2 blocks/CU, all co-resident)

typedef unsigned short u16;
typedef u16    u16x8  __attribute__((ext_vector_type(8)));
typedef u16    u16x4  __attribute__((ext_vector_type(4)));
typedef __bf16 bf16x8 __attribute__((ext_vector_type(8)));
typedef float  f32x4  __attribute__((ext_vector_type(4)));

__device__ __forceinline__ u16 f2bf(float f) {
    unsigned u = __builtin_bit_cast(unsigned, f);
    unsigned r = (u + 0x7fffu + ((u >> 16) & 1u)) >> 16;   // RNE, finite inputs
    return (u16)r;
}
__device__ __forceinline__ float bf2f(u16 u) {
    return __builtin_bit_cast(float, (unsigned)u << 16);
}
__device__ __forceinline__ float rcpf(float x) { return __builtin_amdgcn_rcpf(x); }

// async global->LDS, 16B per lane; lds base wave-uniform, lane deposits at
// base + laneid*16  [guide §5, m97/m104]
__device__ __forceinline__ void async16(const void* g, void* lds) {
    __builtin_amdgcn_global_load_lds(
        (const __attribute__((address_space(1))) unsigned int*)g,
        (__attribute__((address_space(3))) unsigned int*)lds, 16, 0, 0);
}

// device-scope spin barrier: one counter per barrier instance per launch
// (counters zeroed by the memset each call). Safe: all MIDBLK blocks are
// co-resident (LDS 39.3KB -> 4 blocks/CU cap; 512 = 2/CU placed at dispatch).
__device__ __forceinline__ void gbar(unsigned* ctr) {
    __syncthreads();                       // drains each wave's vmcnt first
    if (threadIdx.x == 0) {
        __hip_atomic_fetch_add(ctr, 1u, __ATOMIC_RELEASE, __HIP_MEMORY_SCOPE_AGENT);
        while (__hip_atomic_load(ctr, __ATOMIC_ACQUIRE, __HIP_MEMORY_SCOPE_AGENT) < (unsigned)MIDBLK)
            __builtin_amdgcn_s_sleep(2);
    }
    __syncthreads();
}

// ---------------- fused fp32 -> bf16 conversion of x, Wqkv, Wout ----------------
__global__ __launch_bounds__(256) void cvt3(
        const float4* __restrict__ x, const float4* __restrict__ wq, const float4* __restrict__ wo,
        u16x4* __restrict__ ox, u16x4* __restrict__ owq, u16x4* __restrict__ owo) {
    const int n1 = NPOS * E_ / 4, n2 = QKVC * E_ / 4, n3 = E_ * E_ / 4;
    int i = blockIdx.x * 256 + threadIdx.x;
    const float4* in; u16x4* out; int j;
    if (i < n1)            { in = x;  out = ox;  j = i; }
    else if (i < n1 + n2)  { in = wq; out = owq; j = i - n1; }
    else if (i < n1+n2+n3) { in = wo; out = owo; j = i - n1 - n2; }
    else return;
    float4 v = in[j];
    u16x4 o;
    o[0] = f2bf(v.x); o[1] = f2bf(v.y); o[2] = f2bf(v.z); o[3] = f2bf(v.w);
    out[j] = o;
}

// ---------------- GEMM1: qkv = sigmoid_qk(x @ Wqkv^T + b), de-interleaved bf16 out ----------------
// m97 structure, 128x128 tile.  Epilogue also accumulates per-batch column
// sums of sigmoided q,k into sumq/sumk via atomicAdd (replaces sum_qk kernel).
__global__ __launch_bounds__(256) void gemm_qkv(
        const u16* __restrict__ A, const u16* __restrict__ Bw,
        const float* __restrict__ bias,
        u16* __restrict__ Qb, u16* __restrict__ Kb, u16* __restrict__ Vb,
        float* __restrict__ sumq, float* __restrict__ sumk,
        int K) {
    __shared__ u16 As[128 * 32];
    __shared__ u16 Bs[128 * 32];
    const int tid  = threadIdx.x;
    const int wave = tid >> 6, lane = tid & 63;
    const int m0 = blockIdx.y * 128, n0 = blockIdx.x * 128;
    const int wm = (wave & 1) * 64, wn = (wave >> 1) * 64;

    const int srow = wave * 16 + (lane >> 2);
    const int scol = (lane & 3) * 8;
    const u16* Ap = A  + (size_t)(m0 + srow) * K + scol;
    const u16* Bp = Bw + (size_t)(n0 + srow) * K + scol;
    u16* AsW = &As[wave * 512];
    u16* BsW = &Bs[wave * 512];
    const size_t rstep = (size_t)64 * K;

    f32x4 acc[4][4] = {};
    const int fr = lane & 15, fk = (lane >> 4) * 8;

    for (int k0 = 0; k0 < K; k0 += 32) {
        async16(Ap + k0,         AsW);
        async16(Ap + k0 + rstep, AsW + 2048);
        async16(Bp + k0,         BsW);
        async16(Bp + k0 + rstep, BsW + 2048);
        __syncthreads();
        bf16x8 a[4], b[4];
        #pragma unroll
        for (int i = 0; i < 4; ++i)
            a[i] = *(const bf16x8*)&As[(wm + i * 16 + fr) * 32 + fk];
        #pragma unroll
        for (int j = 0; j < 4; ++j)
            b[j] = *(const bf16x8*)&Bs[(wn + j * 16 + fr) * 32 + fk];
        #pragma unroll
        for (int i = 0; i < 4; ++i)
            #pragma unroll
            for (int j = 0; j < 4; ++j)
                acc[i][j] = __builtin_amdgcn_mfma_f32_16x16x32_bf16(a[i], b[j], acc[i][j], 0, 0, 0);
        __syncthreads();
    }

    // epilogue: C/D col = lane&15, row = (lane>>4)*4 + reg   [m89/m91]
    const int cn = lane & 15, rb = (lane >> 4) * 4;
    const int cg   = (n0 + wn) >> 6;      // wave-uniform 64-col group
    const int type = cg % 3;              // 0=q, 1=k, 2=v
    const int hb   = cg / 3;
    const int bb   = m0 >> 12;            // batch (tiles don't straddle: 128|4096)
    u16* dst = (type == 0) ? Qb : (type == 1) ? Kb : Vb;
    float* ssum = (type == 0) ? sumq : sumk;
    const bool sg = (type < 2);
    #pragma unroll
    for (int j = 0; j < 4; ++j) {
        int ccol = j * 16 + cn;                     // 0..63 within group
        float bv = bias[n0 + wn + ccol];
        int outcol = hb * 64 + ccol;
        float csum = 0.f;
        #pragma unroll
        for (int i = 0; i < 4; ++i) {
            int mbase = m0 + wm + i * 16 + rb;
            f32x4 av = acc[i][j];
            #pragma unroll
            for (int r = 0; r < 4; ++r) {
                float v = av[r] + bv;
                if (sg) v = 1.f / (1.f + __expf(-v));
                csum += v;
                dst[(size_t)(mbase + r) * 512 + outcol] = f2bf(v);
            }
        }
        if (sg) {   // reduce 4 quads -> full 64-row wave sum, one atomic/column
            csum += __shfl_xor(csum, 16);
            csum += __shfl_xor(csum, 32);
            if (lane < 16) atomicAdd(&ssum[bb * 512 + outcol], csum);
        }
    }
}

// ---------------- GEMM2: out = r @ Wout^T + b (fp32 out) ----------------
__global__ __launch_bounds__(256) void gemm_out(
        const u16* __restrict__ A, const u16* __restrict__ Bw,
        const float* __restrict__ bias, float* __restrict__ C,
        int N, int K) {
    __shared__ u16 As[128 * 32];
    __shared__ u16 Bs[128 * 32];
    const int tid  = threadIdx.x;
    const int wave = tid >> 6, lane = tid & 63;
    const int m0 = blockIdx.y * 128, n0 = blockIdx.x * 128;
    const int wm = (wave & 1) * 64, wn = (wave >> 1) * 64;
    const int srow = wave * 16 + (lane >> 2);
    const int scol = (lane & 3) * 8;
    const u16* Ap = A  + (size_t)(m0 + srow) * K + scol;
    const u16* Bp = Bw + (size_t)(n0 + srow) * K + scol;
    u16* AsW = &As[wave * 512];
    u16* BsW = &Bs[wave * 512];
    const size_t rstep = (size_t)64 * K;
    f32x4 acc[4][4] = {};
    const int fr = lane & 15, fk = (lane >> 4) * 8;
    for (int k0 = 0; k0 < K; k0 += 32) {
        async16(Ap + k0,         AsW);
        async16(Ap + k0 + rstep, AsW + 2048);
        async16(Bp + k0,         BsW);
        async16(Bp + k0 + rstep, BsW + 2048);
        __syncthreads();
        bf16x8 a[4], b[4];
        #pragma unroll
        for (int i = 0; i < 4; ++i)
            a[i] = *(const bf16x8*)&As[(wm + i * 16 + fr) * 32 + fk];
        #pragma unroll
        for (int j = 0; j < 4; ++j)
            b[j] = *(const bf16x8*)&Bs[(wn + j * 16 + fr) * 32 + fk];
        #pragma unroll
        for (int i = 0; i < 4; ++i)
            #pragma unroll
            for (int j = 0; j < 4; ++j)
                acc[i][j] = __builtin_amdgcn_mfma_f32_16x16x32_bf16(a[i], b[j], acc[i][j], 0, 0, 0);
        __syncthreads();
    }
    const int cn = lane & 15, rb = (lane >> 4) * 4;
    #pragma unroll
    for (int i = 0; i < 4; ++i) {
        int mbase = m0 + wm + i * 16 + rb;
        #pragma unroll
        for (int j = 0; j < 4; ++j) {
            int nn = n0 + wn + j * 16 + cn;
            float bv = bias[nn];
            f32x4 av = acc[i][j];
            #pragma unroll
            for (int r = 0; r < 4; ++r)
                C[(size_t)(mbase + r) * N + nn] = av[r] + bv;
        }
    }
}

// ---------------- fused middle: io-dots + io2 + finalize, spin-barrier synced ----------------
// grid MUST be MIDBLK=512 blocks x 256 threads.
// Block: b = blk>>7, sc = blk&127; covers 32 positions.
__global__ __launch_bounds__(256) void mid_kernel(
        const u16* __restrict__ Qg, const u16* __restrict__ Kg, const u16* __restrict__ Vg,
        const float* __restrict__ sumq, const float* __restrict__ sumk,
        float* __restrict__ sumqi, float* __restrict__ sumko, float* __restrict__ sm,
        unsigned* __restrict__ bar0, unsigned* __restrict__ bar1,
        u16* __restrict__ Rg) {
    __shared__ float red[4][1024];      // stage-1 cross-wave reduction (16 KB)
    __shared__ float ivs[32][8];        // i  per (local pos, h)
    __shared__ float rsc[32][8];        // sig(i_hat)/i
    __shared__ float wxp[32][8];        // exp(o_hat)
    __shared__ float smr[4][8];
    __shared__ float Ml[4][2][8][9];
    __shared__ float vw[4][2][8][68];

    const int b = blockIdx.x >> 7, sc = blockIdx.x & 127;
    const int pbase = b * S_ + sc * 32;
    const int w = threadIdx.x >> 6, lane = threadIdx.x & 63;
    const int tid = threadIdx.x;
    const int p0 = pbase + w * 8;

    // ---- stage 1: i,o dots + partial sums of q/i, k/o ----
    {
        float skL[8], sqL[8];
        #pragma unroll
        for (int j = 0; j < 8; ++j) {
            skL[j] = sumk[b * 512 + lane * 8 + j];
            sqL[j] = sumq[b * 512 + lane * 8 + j];
        }
        float aqi[8] = {}, ako[8] = {};
        for (int it = 0; it < 8; ++it) {
            int p = p0 + it;
            size_t off = (size_t)p * 512 + lane * 8;
            u16x8 q8 = *(const u16x8*)(Qg + off);
            u16x8 k8 = *(const u16x8*)(Kg + off);
            float qf[8], kf[8];
            #pragma unroll
            for (int j = 0; j < 8; ++j) { qf[j] = bf2f(q8[j]); kf[j] = bf2f(k8[j]); }
            float di = 0.f, dox = 0.f;
            #pragma unroll
            for (int j = 0; j < 8; ++j) { di += qf[j] * skL[j]; dox += kf[j] * sqL[j]; }
            di  += __shfl_xor(di, 1);  di  += __shfl_xor(di, 2);  di  += __shfl_xor(di, 4);
            dox += __shfl_xor(dox, 1); dox += __shfl_xor(dox, 2); dox += __shfl_xor(dox, 4);
            if ((lane & 7) == 0) ivs[w * 8 + it][lane >> 3] = di;
            float ri = rcpf(di), ro = rcpf(dox);
            #pragma unroll
            for (int j = 0; j < 8; ++j) { aqi[j] += qf[j] * ri; ako[j] += kf[j] * ro; }
        }
        #pragma unroll
        for (int j = 0; j < 8; ++j) {
            red[w][lane * 8 + j]       = aqi[j];
            red[w][512 + lane * 8 + j] = ako[j];
        }
        __syncthreads();
        #pragma unroll
        for (int rr = 0; rr < 4; ++rr) {
            int slot = rr * 256 + tid;
            float s = red[0][slot] + red[1][slot] + red[2][slot] + red[3][slot];
            float* dstp = (slot < 512) ? &sumqi[b * 512 + slot] : &sumko[b * 512 + (slot - 512)];
            atomicAdd(dstp, s);
        }
    }
    gbar(bar0);

    // ---- stage 2: i_hat, o_hat -> rsc, wxp (LDS) + sm atomics ----
    {
        float skoL[8], sqiL[8];
        #pragma unroll
        for (int j = 0; j < 8; ++j) {
            skoL[j] = sumko[b * 512 + lane * 8 + j];
            sqiL[j] = sumqi[b * 512 + lane * 8 + j];
        }
        float smacc = 0.f;
        for (int it = 0; it < 8; ++it) {
            int p = p0 + it;
            size_t off = (size_t)p * 512 + lane * 8;
            u16x8 q8 = *(const u16x8*)(Qg + off);
            u16x8 k8 = *(const u16x8*)(Kg + off);
            float dih = 0.f, doh = 0.f;
            #pragma unroll
            for (int j = 0; j < 8; ++j) {
                dih += bf2f(q8[j]) * skoL[j];
                doh += bf2f(k8[j]) * sqiL[j];
            }
            dih += __shfl_xor(dih, 1); dih += __shfl_xor(dih, 2); dih += __shfl_xor(dih, 4);
            doh += __shfl_xor(doh, 1); doh += __shfl_xor(doh, 2); doh += __shfl_xor(doh, 4);
            if ((lane & 7) == 0) {
                int pi = w * 8 + it, h = lane >> 3;
                float sig = 1.f / (1.f + __expf(-dih));
                rsc[pi][h] = sig * rcpf(ivs[pi][h]);
                float we = __expf(fminf(doh, 80.f));   // o_hat ~ O(1); no max-sub needed
                wxp[pi][h] = we;
                smacc += we;
            }
        }
        if ((lane & 7) == 0) smr[w][lane >> 3] = smacc;
        __syncthreads();
        if (tid < 8)
            atomicAdd(&sm[b * 8 + tid], smr[0][tid] + smr[1][tid] + smr[2][tid] + smr[3][tid]);
    }
    gbar(bar1);

    // ---- stage 3: per-position 8x8 head mix -> r (bf16); 2 positions per wave-iter ----
    const float invsm = rcpf(sm[b * 8 + (lane >> 3)]);   // for vw role (hv = lane>>3)
    for (int it2 = 0; it2 < 4; ++it2) {
        int pl0 = w * 8 + it2 * 2;       // local position index of pair
        int pp = pbase + pl0;
        // QK^T via MFMA: A rows m=(p_l,h) from Q, B rows n=(p_l,h2) from K
        {
            int pl = (lane >> 3) & 1, hh = lane & 7, quad = lane >> 4;
            const u16* qa = Qg + (size_t)(pp + pl) * 512 + hh * 64 + quad * 8;
            const u16* ka = Kg + (size_t)(pp + pl) * 512 + hh * 64 + quad * 8;
            bf16x8 a0 = __builtin_bit_cast(bf16x8, *(const u16x8*)qa);
            bf16x8 a1 = __builtin_bit_cast(bf16x8, *(const u16x8*)(qa + 32));
            bf16x8 b0 = __builtin_bit_cast(bf16x8, *(const u16x8*)ka);
            bf16x8 b1 = __builtin_bit_cast(bf16x8, *(const u16x8*)(ka + 32));
            f32x4 accm = {0.f, 0.f, 0.f, 0.f};
            accm = __builtin_amdgcn_mfma_f32_16x16x32_bf16(a0, b0, accm, 0, 0, 0);
            accm = __builtin_amdgcn_mfma_f32_16x16x32_bf16(a1, b1, accm, 0, 0, 0);
            // C: row=(lane>>4)*4+r, col=lane&15.  Keep diagonal p-quadrants.
            if (((lane >> 5) & 1) == ((lane >> 3) & 1)) {
                int plm = lane >> 5, hr = ((lane >> 4) & 1) * 4, h2 = lane & 7;
                #pragma unroll
                for (int r = 0; r < 4; ++r)
                    Ml[w][plm][hr + r][h2] = accm[r] * rsc[pl0 + plm][hr + r];
            }
        }
        // vw = v * softmax-weight (fp32, LDS)
        {
            int hv = lane >> 3, e0 = (lane & 7) * 8;
            #pragma unroll
            for (int pl = 0; pl < 2; ++pl) {
                u16x8 v8 = *(const u16x8*)(Vg + (size_t)(pp + pl) * 512 + lane * 8);
                float wgt = wxp[pl0 + pl][hv] * invsm;
                f32x4 x0, x1;
                #pragma unroll
                for (int j = 0; j < 4; ++j) { x0[j] = bf2f(v8[j]) * wgt; x1[j] = bf2f(v8[4 + j]) * wgt; }
                *(f32x4*)&vw[w][pl][hv][e0]     = x0;
                *(f32x4*)&vw[w][pl][hv][e0 + 4] = x1;
            }
        }
        __syncthreads();
        // PV: lane covers (p_l = lane>>5, h = (lane&31)>>2, 16-elem e-chunk)
        {
            int pl = lane >> 5, idx = lane & 31, h = idx >> 2, eq = (idx & 3) * 16;
            float outv[16] = {};
            #pragma unroll
            for (int h2 = 0; h2 < 8; ++h2) {
                float m = Ml[w][pl][h][h2];
                #pragma unroll
                for (int c = 0; c < 4; ++c) {
                    f32x4 vv = *(const f32x4*)&vw[w][pl][h2][eq + c * 4];
                    #pragma unroll
                    for (int j = 0; j < 4; ++j) outv[c * 4 + j] += m * vv[j];
                }
            }
            u16x8 o0, o1;
            #pragma unroll
            for (int j = 0; j < 8; ++j) { o0[j] = f2bf(outv[j]); o1[j] = f2bf(outv[8 + j]); }
            u16* dstp = Rg + (size_t)(pp + pl) * 512 + h * 64 + eq;
            *(u16x8*)dstp       = o0;
            *(u16x8*)(dstp + 8) = o1;
        }
        __syncthreads();   // protect Ml/vw before next iteration overwrites
    }
}

// ---------------- launch ----------------
extern "C" void kernel_launch(void* const* d_in, const int* in_sizes, int n_in,
                              void* d_out, int out_size, void* d_ws, size_t ws_size,
                              hipStream_t stream) {
    const float* x    = (const float*)d_in[0];
    const float* Wqkv = (const float*)d_in[1];
    const float* bqkv = (const float*)d_in[2];
    const float* Wout = (const float*)d_in[3];
    const float* bout = (const float*)d_in[4];
    float* out = (float*)d_out;
    char* ws = (char*)d_ws;

    constexpr size_t SZ_XBF  = (size_t)NPOS * E_ * 2;     // 16 MB (reused for r)
    constexpr size_t SZ_WQBF = (size_t)QKVC * E_ * 2;
    constexpr size_t SZ_WOBF = (size_t)E_ * E_ * 2;
    constexpr size_t SZ_QKVB = (size_t)NPOS * E_ * 2;     // 16 MB each of Q,K,V
    constexpr size_t SZ_SUM  = (size_t)B_ * 512 * 4;      // 8 KB each

    size_t off = 0;
    u16*   xbf   = (u16*)(ws + off);   off += SZ_XBF;
    u16*   wqbf  = (u16*)(ws + off);   off += SZ_WQBF;
    u16*   wobf  = (u16*)(ws + off);   off += SZ_WOBF;
    u16*   Qb    = (u16*)(ws + off);   off += SZ_QKVB;
    u16*   Kb    = (u16*)(ws + off);   off += SZ_QKVB;
    u16*   Vb    = (u16*)(ws + off);   off += SZ_QKVB;
    char*  zbase = ws + off;                       // contiguous zeroed region:
    float* sumq  = (float*)(ws + off); off += SZ_SUM;
    float* sumk  = (float*)(ws + off); off += SZ_SUM;
    float* sumqi = (float*)(ws + off); off += SZ_SUM;
    float* sumko = (float*)(ws + off); off += SZ_SUM;
    float* sm    = (float*)(ws + off); off += 256;
    unsigned* bar0 = (unsigned*)(ws + off); off += 128;
    unsigned* bar1 = (unsigned*)(ws + off); off += 128;
    size_t zlen  = (char*)(ws + off) - zbase;
    u16*   rbf   = xbf;   // reuse after GEMM1

    hipMemsetAsync(zbase, 0, zlen, stream);

    // fused conversions
    {
        const int n4 = (NPOS * E_ + QKVC * E_ + E_ * E_) / 4;
        cvt3<<<(n4 + 255) / 256, 256, 0, stream>>>(
            (const float4*)x, (const float4*)Wqkv, (const float4*)Wout,
            (u16x4*)xbf, (u16x4*)wqbf, (u16x4*)wobf);
    }

    // GEMM1 with fused sigmoid + de-interleave + column sums
    gemm_qkv<<<dim3(QKVC / 128, NPOS / 128), 256, 0, stream>>>(
        xbf, wqbf, bqkv, Qb, Kb, Vb, sumq, sumk, K_);

    // fused middle (regular launch + device-scope spin barriers)
    mid_kernel<<<MIDBLK, 256, 0, stream>>>(
        Qb, Kb, Vb, sumq, sumk, sumqi, sumko, sm, bar0, bar1, rbf);

    // GEMM2
    gemm_out<<<dim3(E_ / 128, NPOS / 128), 256, 0, stream>>>(
        rbf, wobf, bout, out, E_, K_);
}

// Round 7
// 226.240 us; speedup vs baseline: 1.1894x; 1.1894x over previous
//
#include <hip/hip_runtime.h>
#include <cstdint>
#include <cstddef>

// ---------------- problem constants ----------------
#define B_ 4
#define S_ 4096
#define E_ 512
#define NPOS 16384      // B*S
#define QKVC 1536       // 3*E
#define K_ 512          // contraction dim of both GEMMs

typedef unsigned short u16;
typedef u16    u16x8  __attribute__((ext_vector_type(8)));
typedef u16    u16x4  __attribute__((ext_vector_type(4)));
typedef __bf16 bf16x8 __attribute__((ext_vector_type(8)));
typedef float  f32x4  __attribute__((ext_vector_type(4)));

__device__ __forceinline__ u16 f2bf(float f) {
    unsigned u = __builtin_bit_cast(unsigned, f);
    unsigned r = (u + 0x7fffu + ((u >> 16) & 1u)) >> 16;   // RNE, finite inputs
    return (u16)r;
}
__device__ __forceinline__ float bf2f(u16 u) {
    return __builtin_bit_cast(float, (unsigned)u << 16);
}
__device__ __forceinline__ float rcpf(float x) { return __builtin_amdgcn_rcpf(x); }

// async global->LDS, 16B per lane; lds base wave-uniform, lane deposits at
// base + laneid*16  [guide §5, m97/m104]
__device__ __forceinline__ void async16(const void* g, void* lds) {
    __builtin_amdgcn_global_load_lds(
        (const __attribute__((address_space(1))) unsigned int*)g,
        (__attribute__((address_space(3))) unsigned int*)lds, 16, 0, 0);
}

// ---------------- fused fp32 -> bf16 conversion of x, Wqkv, Wout ----------------
__global__ __launch_bounds__(256) void cvt3(
        const float4* __restrict__ x, const float4* __restrict__ wq, const float4* __restrict__ wo,
        u16x4* __restrict__ ox, u16x4* __restrict__ owq, u16x4* __restrict__ owo) {
    const int n1 = NPOS * E_ / 4, n2 = QKVC * E_ / 4, n3 = E_ * E_ / 4;
    int i = blockIdx.x * 256 + threadIdx.x;
    const float4* in; u16x4* out; int j;
    if (i < n1)            { in = x;  out = ox;  j = i; }
    else if (i < n1 + n2)  { in = wq; out = owq; j = i - n1; }
    else if (i < n1+n2+n3) { in = wo; out = owo; j = i - n1 - n2; }
    else return;
    float4 v = in[j];
    u16x4 o;
    o[0] = f2bf(v.x); o[1] = f2bf(v.y); o[2] = f2bf(v.z); o[3] = f2bf(v.w);
    out[j] = o;
}

// ---------------- GEMM1: qkv = sigmoid_qk(x @ Wqkv^T + b), de-interleaved bf16 out ----------------
// m97 structure, 128x128 tile.  NO epilogue reductions (R5: fused atomics cost ~60us).
__global__ __launch_bounds__(256) void gemm_qkv(
        const u16* __restrict__ A, const u16* __restrict__ Bw,
        const float* __restrict__ bias,
        u16* __restrict__ Qb, u16* __restrict__ Kb, u16* __restrict__ Vb,
        int K) {
    __shared__ u16 As[128 * 32];
    __shared__ u16 Bs[128 * 32];
    const int tid  = threadIdx.x;
    const int wave = tid >> 6, lane = tid & 63;
    const int m0 = blockIdx.y * 128, n0 = blockIdx.x * 128;
    const int wm = (wave & 1) * 64, wn = (wave >> 1) * 64;

    const int srow = wave * 16 + (lane >> 2);
    const int scol = (lane & 3) * 8;
    const u16* Ap = A  + (size_t)(m0 + srow) * K + scol;
    const u16* Bp = Bw + (size_t)(n0 + srow) * K + scol;
    u16* AsW = &As[wave * 512];
    u16* BsW = &Bs[wave * 512];
    const size_t rstep = (size_t)64 * K;

    f32x4 acc[4][4] = {};
    const int fr = lane & 15, fk = (lane >> 4) * 8;

    for (int k0 = 0; k0 < K; k0 += 32) {
        async16(Ap + k0,         AsW);
        async16(Ap + k0 + rstep, AsW + 2048);
        async16(Bp + k0,         BsW);
        async16(Bp + k0 + rstep, BsW + 2048);
        __syncthreads();
        bf16x8 a[4], b[4];
        #pragma unroll
        for (int i = 0; i < 4; ++i)
            a[i] = *(const bf16x8*)&As[(wm + i * 16 + fr) * 32 + fk];
        #pragma unroll
        for (int j = 0; j < 4; ++j)
            b[j] = *(const bf16x8*)&Bs[(wn + j * 16 + fr) * 32 + fk];
        #pragma unroll
        for (int i = 0; i < 4; ++i)
            #pragma unroll
            for (int j = 0; j < 4; ++j)
                acc[i][j] = __builtin_amdgcn_mfma_f32_16x16x32_bf16(a[i], b[j], acc[i][j], 0, 0, 0);
        __syncthreads();
    }

    // epilogue: C/D col = lane&15, row = (lane>>4)*4 + reg   [m89/m91]
    const int cn = lane & 15, rb = (lane >> 4) * 4;
    const int cg   = (n0 + wn) >> 6;      // wave-uniform 64-col group
    const int type = cg % 3;              // 0=q, 1=k, 2=v
    const int hb   = cg / 3;
    u16* dst = (type == 0) ? Qb : (type == 1) ? Kb : Vb;
    const bool sg = (type < 2);
    #pragma unroll
    for (int i = 0; i < 4; ++i) {
        int mbase = m0 + wm + i * 16 + rb;
        #pragma unroll
        for (int j = 0; j < 4; ++j) {
            int ccol = j * 16 + cn;
            float bv = bias[n0 + wn + ccol];
            int outcol = hb * 64 + ccol;
            f32x4 av = acc[i][j];
            #pragma unroll
            for (int r = 0; r < 4; ++r) {
                float v = av[r] + bv;
                if (sg) v = 1.f / (1.f + __expf(-v));
                dst[(size_t)(mbase + r) * 512 + outcol] = f2bf(v);
            }
        }
    }
}

// ---------------- GEMM2: out = r @ Wout^T + b (fp32 out) ----------------
__global__ __launch_bounds__(256) void gemm_out(
        const u16* __restrict__ A, const u16* __restrict__ Bw,
        const float* __restrict__ bias, float* __restrict__ C,
        int N, int K) {
    __shared__ u16 As[128 * 32];
    __shared__ u16 Bs[128 * 32];
    const int tid  = threadIdx.x;
    const int wave = tid >> 6, lane = tid & 63;
    const int m0 = blockIdx.y * 128, n0 = blockIdx.x * 128;
    const int wm = (wave & 1) * 64, wn = (wave >> 1) * 64;
    const int srow = wave * 16 + (lane >> 2);
    const int scol = (lane & 3) * 8;
    const u16* Ap = A  + (size_t)(m0 + srow) * K + scol;
    const u16* Bp = Bw + (size_t)(n0 + srow) * K + scol;
    u16* AsW = &As[wave * 512];
    u16* BsW = &Bs[wave * 512];
    const size_t rstep = (size_t)64 * K;
    f32x4 acc[4][4] = {};
    const int fr = lane & 15, fk = (lane >> 4) * 8;
    for (int k0 = 0; k0 < K; k0 += 32) {
        async16(Ap + k0,         AsW);
        async16(Ap + k0 + rstep, AsW + 2048);
        async16(Bp + k0,         BsW);
        async16(Bp + k0 + rstep, BsW + 2048);
        __syncthreads();
        bf16x8 a[4], b[4];
        #pragma unroll
        for (int i = 0; i < 4; ++i)
            a[i] = *(const bf16x8*)&As[(wm + i * 16 + fr) * 32 + fk];
        #pragma unroll
        for (int j = 0; j < 4; ++j)
            b[j] = *(const bf16x8*)&Bs[(wn + j * 16 + fr) * 32 + fk];
        #pragma unroll
        for (int i = 0; i < 4; ++i)
            #pragma unroll
            for (int j = 0; j < 4; ++j)
                acc[i][j] = __builtin_amdgcn_mfma_f32_16x16x32_bf16(a[i], b[j], acc[i][j], 0, 0, 0);
        __syncthreads();
    }
    const int cn = lane & 15, rb = (lane >> 4) * 4;
    #pragma unroll
    for (int i = 0; i < 4; ++i) {
        int mbase = m0 + wm + i * 16 + rb;
        #pragma unroll
        for (int j = 0; j < 4; ++j) {
            int nn = n0 + wn + j * 16 + cn;
            float bv = bias[nn];
            f32x4 av = acc[i][j];
            #pragma unroll
            for (int r = 0; r < 4; ++r)
                C[(size_t)(mbase + r) * N + nn] = av[r] + bv;
        }
    }
}

// ---------------- sum_qk: partial sums over s of q,k  (grid 1024 x 256) ----------------
// Block covers 16 positions (4 per wave). Partials: [b][256 chunks][1024].
__global__ __launch_bounds__(256, 4) void sum_qk(
        const u16* __restrict__ Qg, const u16* __restrict__ Kg,
        float* __restrict__ part) {
    __shared__ float red[4][1024];
    const int blk = blockIdx.x;
    const int b = blk >> 8, chunk = blk & 255;
    const int w = threadIdx.x >> 6, lane = threadIdx.x & 63;
    const int p0 = b * S_ + chunk * 16 + w * 4;
    float aq[8] = {}, ak[8] = {};
    #pragma unroll
    for (int it = 0; it < 4; ++it) {
        size_t off = (size_t)(p0 + it) * 512 + lane * 8;
        u16x8 q8 = *(const u16x8*)(Qg + off);
        u16x8 k8 = *(const u16x8*)(Kg + off);
        #pragma unroll
        for (int j = 0; j < 8; ++j) { aq[j] += bf2f(q8[j]); ak[j] += bf2f(k8[j]); }
    }
    #pragma unroll
    for (int j = 0; j < 8; ++j) {
        red[w][lane * 8 + j]       = aq[j];
        red[w][512 + lane * 8 + j] = ak[j];
    }
    __syncthreads();
    const int tid = threadIdx.x;
    float* dst = part + (size_t)blk * 1024;
    #pragma unroll
    for (int rr = 0; rr < 4; ++rr) {
        int slot = rr * 256 + tid;
        dst[slot] = red[0][slot] + red[1][slot] + red[2][slot] + red[3][slot];
    }
}

// fold 256 chunk partials -> sumq/sumk  (grid 16 x 256)
__global__ __launch_bounds__(256) void fold_qk(
        const float* __restrict__ part, float* __restrict__ sumq, float* __restrict__ sumk) {
    int t = blockIdx.x * 256 + threadIdx.x;       // 0..4095
    int b = t >> 10, slot = t & 1023;
    float a = 0.f;
    const float* p = part + (size_t)b * 256 * 1024 + slot;
    for (int c = 0; c < 256; ++c) a += p[(size_t)c * 1024];
    if (slot < 512) sumq[b * 512 + slot] = a;
    else            sumk[b * 512 + (slot - 512)] = a;
}

// ---------------- P2: i,o dots + partial sums of q/i, k/o  (grid 2048 x 256) ----------------
// Block covers 8 positions (2 per wave). Partials: [b][512 chunks][1024].
__global__ __launch_bounds__(256, 4) void p2_io(
        const u16* __restrict__ Qg, const u16* __restrict__ Kg,
        const float* __restrict__ sumq, const float* __restrict__ sumk,
        float* __restrict__ iv, float* __restrict__ part) {
    __shared__ float red[4][1024];
    const int blk = blockIdx.x;
    const int b = blk >> 9, chunk = blk & 511;
    const int w = threadIdx.x >> 6, lane = threadIdx.x & 63;
    const int p0 = b * S_ + chunk * 8 + w * 2;
    float skL[8], sqL[8];
    #pragma unroll
    for (int j = 0; j < 8; ++j) {
        skL[j] = sumk[b * 512 + lane * 8 + j];
        sqL[j] = sumq[b * 512 + lane * 8 + j];
    }
    float aqi[8] = {}, ako[8] = {};
    #pragma unroll
    for (int it = 0; it < 2; ++it) {
        int p = p0 + it;
        size_t off = (size_t)p * 512 + lane * 8;
        u16x8 q8 = *(const u16x8*)(Qg + off);
        u16x8 k8 = *(const u16x8*)(Kg + off);
        float qf[8], kf[8];
        #pragma unroll
        for (int j = 0; j < 8; ++j) { qf[j] = bf2f(q8[j]); kf[j] = bf2f(k8[j]); }
        float di = 0.f, dox = 0.f;
        #pragma unroll
        for (int j = 0; j < 8; ++j) { di += qf[j] * skL[j]; dox += kf[j] * sqL[j]; }
        di  += __shfl_xor(di, 1);  di  += __shfl_xor(di, 2);  di  += __shfl_xor(di, 4);
        dox += __shfl_xor(dox, 1); dox += __shfl_xor(dox, 2); dox += __shfl_xor(dox, 4);
        if ((lane & 7) == 0) iv[(size_t)p * 8 + (lane >> 3)] = di;
        float ri = rcpf(di), ro = rcpf(dox);
        #pragma unroll
        for (int j = 0; j < 8; ++j) { aqi[j] += qf[j] * ri; ako[j] += kf[j] * ro; }
    }
    #pragma unroll
    for (int j = 0; j < 8; ++j) {
        red[w][lane * 8 + j]       = aqi[j];
        red[w][512 + lane * 8 + j] = ako[j];
    }
    __syncthreads();
    const int tid = threadIdx.x;
    float* dst = part + (size_t)blk * 1024;
    #pragma unroll
    for (int rr = 0; rr < 4; ++rr) {
        int slot = rr * 256 + tid;
        dst[slot] = red[0][slot] + red[1][slot] + red[2][slot] + red[3][slot];
    }
}

// fold 512 chunk partials -> sumqi/sumko  (grid 16 x 256)
__global__ __launch_bounds__(256) void fold_io(
        const float* __restrict__ part, float* __restrict__ sumqi, float* __restrict__ sumko) {
    int t = blockIdx.x * 256 + threadIdx.x;
    int b = t >> 10, slot = t & 1023;
    float a = 0.f;
    const float* p = part + (size_t)b * 512 * 1024 + slot;
    for (int c = 0; c < 512; ++c) a += p[(size_t)c * 1024];
    if (slot < 512) sumqi[b * 512 + slot] = a;
    else            sumko[b * 512 + (slot - 512)] = a;
}

// ---------------- P3: i_hat,o_hat -> rsc, wexp, sm partials  (grid 2048 x 256) ----------------
__global__ __launch_bounds__(256, 4) void p3_io2(
        const u16* __restrict__ Qg, const u16* __restrict__ Kg,
        const float* __restrict__ sumqi, const float* __restrict__ sumko,
        const float* __restrict__ iv,
        float* __restrict__ rsc, float* __restrict__ wexp, float* __restrict__ smpart) {
    __shared__ float smr[4][8];
    const int blk = blockIdx.x;
    const int b = blk >> 9, chunk = blk & 511;
    const int w = threadIdx.x >> 6, lane = threadIdx.x & 63;
    const int p0 = b * S_ + chunk * 8 + w * 2;
    float skoL[8], sqiL[8];
    #pragma unroll
    for (int j = 0; j < 8; ++j) {
        skoL[j] = sumko[b * 512 + lane * 8 + j];
        sqiL[j] = sumqi[b * 512 + lane * 8 + j];
    }
    float smacc = 0.f;
    #pragma unroll
    for (int it = 0; it < 2; ++it) {
        int p = p0 + it;
        size_t off = (size_t)p * 512 + lane * 8;
        u16x8 q8 = *(const u16x8*)(Qg + off);
        u16x8 k8 = *(const u16x8*)(Kg + off);
        float dih = 0.f, doh = 0.f;
        #pragma unroll
        for (int j = 0; j < 8; ++j) {
            dih += bf2f(q8[j]) * skoL[j];
            doh += bf2f(k8[j]) * sqiL[j];
        }
        dih += __shfl_xor(dih, 1); dih += __shfl_xor(dih, 2); dih += __shfl_xor(dih, 4);
        doh += __shfl_xor(doh, 1); doh += __shfl_xor(doh, 2); doh += __shfl_xor(doh, 4);
        if ((lane & 7) == 0) {
            int h = lane >> 3;
            float sig = 1.f / (1.f + __expf(-dih));
            rsc[(size_t)p * 8 + h] = sig * rcpf(iv[(size_t)p * 8 + h]);
            float we = __expf(fminf(doh, 80.f));   // o_hat ~ O(1); no max-sub needed
            wexp[(size_t)p * 8 + h] = we;
            smacc += we;
        }
    }
    // each wave writes all 8 slots of its own row (lanes 0,8,...,56)
    if ((lane & 7) == 0) smr[w][lane >> 3] = smacc;
    __syncthreads();
    if (threadIdx.x < 8)
        smpart[(size_t)blk * 8 + threadIdx.x] =
            smr[0][threadIdx.x] + smr[1][threadIdx.x] + smr[2][threadIdx.x] + smr[3][threadIdx.x];
}

// fold sm partials  (grid 32 x 256): block per (b,h)
__global__ __launch_bounds__(256) void fold_sm(const float* __restrict__ smpart, float* __restrict__ sm) {
    __shared__ float red[256];
    int bh = blockIdx.x;
    int b = bh >> 3, h = bh & 7;
    float a = 0.f;
    for (int c = threadIdx.x; c < 512; c += 256)
        a += smpart[((size_t)b * 512 + c) * 8 + h];
    red[threadIdx.x] = a;
    __syncthreads();
    for (int st = 128; st > 0; st >>= 1) {
        if (threadIdx.x < st) red[threadIdx.x] += red[threadIdx.x + st];
        __syncthreads();
    }
    if (threadIdx.x == 0) sm[bh] = red[0];
}

// ---------------- P4: per-position 8x8 head mix -> r (bf16)  (grid 2048 x 256) ----------------
__global__ __launch_bounds__(256) void finalize_kernel(
        const u16* __restrict__ Qg, const u16* __restrict__ Kg, const u16* __restrict__ Vg,
        const float* __restrict__ rsc, const float* __restrict__ wexp, const float* __restrict__ sm,
        u16* __restrict__ Rg) {
    __shared__ float Ml[4][2][8][9];
    __shared__ float vw[4][2][8][68];
    const int w = threadIdx.x >> 6, lane = threadIdx.x & 63;
    const int pp = blockIdx.x * 8 + w * 2;
    const int b = pp >> 12;

    // QK^T via MFMA: A rows m=(p_l,h) from Q, B rows n=(p_l,h2) from K
    {
        int pl = (lane >> 3) & 1, hh = lane & 7, quad = lane >> 4;
        const u16* qa = Qg + (size_t)(pp + pl) * 512 + hh * 64 + quad * 8;
        const u16* ka = Kg + (size_t)(pp + pl) * 512 + hh * 64 + quad * 8;
        bf16x8 a0 = __builtin_bit_cast(bf16x8, *(const u16x8*)qa);
        bf16x8 a1 = __builtin_bit_cast(bf16x8, *(const u16x8*)(qa + 32));
        bf16x8 b0 = __builtin_bit_cast(bf16x8, *(const u16x8*)ka);
        bf16x8 b1 = __builtin_bit_cast(bf16x8, *(const u16x8*)(ka + 32));
        f32x4 accm = {0.f, 0.f, 0.f, 0.f};
        accm = __builtin_amdgcn_mfma_f32_16x16x32_bf16(a0, b0, accm, 0, 0, 0);
        accm = __builtin_amdgcn_mfma_f32_16x16x32_bf16(a1, b1, accm, 0, 0, 0);
        // C: row=(lane>>4)*4+r, col=lane&15.  Keep diagonal p-quadrants.
        if (((lane >> 5) & 1) == ((lane >> 3) & 1)) {
            int plm = lane >> 5, hr = ((lane >> 4) & 1) * 4, h2 = lane & 7;
            #pragma unroll
            for (int r = 0; r < 4; ++r)
                Ml[w][plm][hr + r][h2] = accm[r] * rsc[(size_t)(pp + plm) * 8 + hr + r];
        }
    }
    // vw = v * softmax-weight (fp32, LDS)
    {
        int hv = lane >> 3, e0 = (lane & 7) * 8;
        float invsm = rcpf(sm[b * 8 + hv]);
        #pragma unroll
        for (int pl = 0; pl < 2; ++pl) {
            u16x8 v8 = *(const u16x8*)(Vg + (size_t)(pp + pl) * 512 + lane * 8);
            float wgt = wexp[(size_t)(pp + pl) * 8 + hv] * invsm;
            f32x4 x0, x1;
            #pragma unroll
            for (int j = 0; j < 4; ++j) { x0[j] = bf2f(v8[j]) * wgt; x1[j] = bf2f(v8[4 + j]) * wgt; }
            *(f32x4*)&vw[w][pl][hv][e0]     = x0;
            *(f32x4*)&vw[w][pl][hv][e0 + 4] = x1;
        }
    }
    __syncthreads();
    // PV: lane covers (p_l = lane>>5, h = (lane&31)>>2, 16-elem e-chunk)
    {
        int pl = lane >> 5, idx = lane & 31, h = idx >> 2, eq = (idx & 3) * 16;
        float outv[16] = {};
        #pragma unroll
        for (int h2 = 0; h2 < 8; ++h2) {
            float m = Ml[w][pl][h][h2];
            #pragma unroll
            for (int c = 0; c < 4; ++c) {
                f32x4 vv = *(const f32x4*)&vw[w][pl][h2][eq + c * 4];
                #pragma unroll
                for (int j = 0; j < 4; ++j) outv[c * 4 + j] += m * vv[j];
            }
        }
        u16x8 o0, o1;
        #pragma unroll
        for (int j = 0; j < 8; ++j) { o0[j] = f2bf(outv[j]); o1[j] = f2bf(outv[8 + j]); }
        u16* dstp = Rg + (size_t)(pp + pl) * 512 + h * 64 + eq;
        *(u16x8*)dstp       = o0;
        *(u16x8*)(dstp + 8) = o1;
    }
}

// ---------------- launch ----------------
extern "C" void kernel_launch(void* const* d_in, const int* in_sizes, int n_in,
                              void* d_out, int out_size, void* d_ws, size_t ws_size,
                              hipStream_t stream) {
    const float* x    = (const float*)d_in[0];
    const float* Wqkv = (const float*)d_in[1];
    const float* bqkv = (const float*)d_in[2];
    const float* Wout = (const float*)d_in[3];
    const float* bout = (const float*)d_in[4];
    float* out = (float*)d_out;
    char* ws = (char*)d_ws;

    constexpr size_t SZ_XBF  = (size_t)NPOS * E_ * 2;     // 16 MB (reused for r)
    constexpr size_t SZ_WQBF = (size_t)QKVC * E_ * 2;
    constexpr size_t SZ_WOBF = (size_t)E_ * E_ * 2;
    constexpr size_t SZ_QKVB = (size_t)NPOS * E_ * 2;     // 16 MB each of Q,K,V
    constexpr size_t SZ_SUM  = (size_t)B_ * 512 * 4;      // 8 KB each
    constexpr size_t SZ_V8   = (size_t)NPOS * 8 * 4;      // 512 KB each
    constexpr size_t SZ_PART = (size_t)2048 * 1024 * 4;   // 8 MB (max of the two uses)

    size_t off = 0;
    u16*   xbf    = (u16*)(ws + off);   off += SZ_XBF;
    u16*   wqbf   = (u16*)(ws + off);   off += SZ_WQBF;
    u16*   wobf   = (u16*)(ws + off);   off += SZ_WOBF;
    u16*   Qb     = (u16*)(ws + off);   off += SZ_QKVB;
    u16*   Kb     = (u16*)(ws + off);   off += SZ_QKVB;
    u16*   Vb     = (u16*)(ws + off);   off += SZ_QKVB;
    float* sumq   = (float*)(ws + off); off += SZ_SUM;
    float* sumk   = (float*)(ws + off); off += SZ_SUM;
    float* sumqi  = (float*)(ws + off); off += SZ_SUM;
    float* sumko  = (float*)(ws + off); off += SZ_SUM;
    float* sm     = (float*)(ws + off); off += 256;
    float* iv     = (float*)(ws + off); off += SZ_V8;
    float* rsc    = (float*)(ws + off); off += SZ_V8;
    float* wexp   = (float*)(ws + off); off += SZ_V8;
    float* smpart = (float*)(ws + off); off += (size_t)2048 * 8 * 4;
    float* part   = (float*)(ws + off); off += SZ_PART;
    u16*   rbf    = xbf;   // reuse after GEMM1

    // 1) conversions
    {
        const int n4 = (NPOS * E_ + QKVC * E_ + E_ * E_) / 4;
        cvt3<<<(n4 + 255) / 256, 256, 0, stream>>>(
            (const float4*)x, (const float4*)Wqkv, (const float4*)Wout,
            (u16x4*)xbf, (u16x4*)wqbf, (u16x4*)wobf);
    }

    // 2) GEMM1 (sigmoid + de-interleave)
    gemm_qkv<<<dim3(QKVC / 128, NPOS / 128), 256, 0, stream>>>(
        xbf, wqbf, bqkv, Qb, Kb, Vb, K_);

    // 3) sum_q, sum_k
    sum_qk<<<1024, 256, 0, stream>>>(Qb, Kb, part);
    fold_qk<<<16, 256, 0, stream>>>(part, sumq, sumk);

    // 4) i,o + partial sums of q/i, k/o
    p2_io<<<2048, 256, 0, stream>>>(Qb, Kb, sumq, sumk, iv, part);
    fold_io<<<16, 256, 0, stream>>>(part, sumqi, sumko);

    // 5) i_hat,o_hat -> rsc, wexp, sm partials
    p3_io2<<<2048, 256, 0, stream>>>(Qb, Kb, sumqi, sumko, iv, rsc, wexp, smpart);
    fold_sm<<<32, 256, 0, stream>>>(smpart, sm);

    // 6) finalize -> r (bf16)
    finalize_kernel<<<2048, 256, 0, stream>>>(Qb, Kb, Vb, rsc, wexp, sm, rbf);

    // 7) GEMM2
    gemm_out<<<dim3(E_ / 128, NPOS / 128), 256, 0, stream>>>(
        rbf, wobf, bout, out, E_, K_);
}

// Round 8
// 201.806 us; speedup vs baseline: 1.3334x; 1.1211x over previous
//
#include <hip/hip_runtime.h>
#include <cstdint>
#include <cstddef>

// ---------------- problem constants ----------------
#define B_ 4
#define S_ 4096
#define E_ 512
#define NPOS 16384      // B*S
#define QKVC 1536       // 3*E
#define K_ 512          // contraction dim of both GEMMs

typedef unsigned short u16;
typedef u16    u16x8  __attribute__((ext_vector_type(8)));
typedef u16    u16x4  __attribute__((ext_vector_type(4)));
typedef __bf16 bf16x8 __attribute__((ext_vector_type(8)));
typedef float  f32x4  __attribute__((ext_vector_type(4)));

__device__ __forceinline__ u16 f2bf(float f) {
    unsigned u = __builtin_bit_cast(unsigned, f);
    unsigned r = (u + 0x7fffu + ((u >> 16) & 1u)) >> 16;   // RNE, finite inputs
    return (u16)r;
}
__device__ __forceinline__ float bf2f(u16 u) {
    return __builtin_bit_cast(float, (unsigned)u << 16);
}
__device__ __forceinline__ float rcpf(float x) { return __builtin_amdgcn_rcpf(x); }

// async global->LDS, 16B per lane; lds base wave-uniform, lane deposits at
// base + laneid*16  [guide §5, m97/m104]
__device__ __forceinline__ void async16(const void* g, void* lds) {
    __builtin_amdgcn_global_load_lds(
        (const __attribute__((address_space(1))) unsigned int*)g,
        (__attribute__((address_space(3))) unsigned int*)lds, 16, 0, 0);
}

// ---------------- fused fp32 -> bf16 conversion of x, Wqkv, Wout ----------------
__global__ __launch_bounds__(256) void cvt3(
        const float4* __restrict__ x, const float4* __restrict__ wq, const float4* __restrict__ wo,
        u16x4* __restrict__ ox, u16x4* __restrict__ owq, u16x4* __restrict__ owo) {
    const int n1 = NPOS * E_ / 4, n2 = QKVC * E_ / 4, n3 = E_ * E_ / 4;
    int i = blockIdx.x * 256 + threadIdx.x;
    const float4* in; u16x4* out; int j;
    if (i < n1)            { in = x;  out = ox;  j = i; }
    else if (i < n1 + n2)  { in = wq; out = owq; j = i - n1; }
    else if (i < n1+n2+n3) { in = wo; out = owo; j = i - n1 - n2; }
    else return;
    float4 v = in[j];
    u16x4 o;
    o[0] = f2bf(v.x); o[1] = f2bf(v.y); o[2] = f2bf(v.z); o[3] = f2bf(v.w);
    out[j] = o;
}

// ---------------- GEMM1: qkv = sigmoid_qk(x @ Wqkv^T + b) ----------------
// m97 structure, 128x128 tile, XOR-swizzled LDS staging (kills bank conflicts:
// global chunk c^(row&3) lands at LDS chunk c; frag read chunk = quad^(fr&3)).
// Epilogue: de-interleaved bf16 Q/K/V stores + NON-ATOMIC per-block column sums
// of sigmoided q,k -> pgem partials (replaces the sum_qk pass; R5 showed the
// atomic version costs ~60us, this one is 2 shfl + 1KB LDS + coalesced stores).
__global__ __launch_bounds__(256) void gemm_qkv(
        const u16* __restrict__ A, const u16* __restrict__ Bw,
        const float* __restrict__ bias,
        u16* __restrict__ Qb, u16* __restrict__ Kb, u16* __restrict__ Vb,
        float* __restrict__ pgem,
        int K) {
    __shared__ u16 As[128 * 32];
    __shared__ u16 Bs[128 * 32];
    __shared__ float csums[2][2][64];   // [wn-half][wm-half][col]
    const int tid  = threadIdx.x;
    const int wave = tid >> 6, lane = tid & 63;
    const int m0 = blockIdx.y * 128, n0 = blockIdx.x * 128;
    const int wm = (wave & 1) * 64, wn = (wave >> 1) * 64;

    const int srow = wave * 16 + (lane >> 2);
    const int scol = (((lane & 3) ^ ((lane >> 2) & 3))) * 8;   // XOR swizzle
    const u16* Ap = A  + (size_t)(m0 + srow) * K + scol;
    const u16* Bp = Bw + (size_t)(n0 + srow) * K + scol;
    u16* AsW = &As[wave * 512];
    u16* BsW = &Bs[wave * 512];
    const size_t rstep = (size_t)64 * K;

    f32x4 acc[4][4] = {};
    const int fr = lane & 15, fq = lane >> 4;
    const int fkA = ((fq ^ (fr & 3))) * 8;                      // swizzled read

    for (int k0 = 0; k0 < K; k0 += 32) {
        async16(Ap + k0,         AsW);
        async16(Ap + k0 + rstep, AsW + 2048);
        async16(Bp + k0,         BsW);
        async16(Bp + k0 + rstep, BsW + 2048);
        __syncthreads();
        bf16x8 a[4], b[4];
        #pragma unroll
        for (int i = 0; i < 4; ++i)
            a[i] = *(const bf16x8*)&As[(wm + i * 16 + fr) * 32 + fkA];
        #pragma unroll
        for (int j = 0; j < 4; ++j)
            b[j] = *(const bf16x8*)&Bs[(wn + j * 16 + fr) * 32 + fkA];
        #pragma unroll
        for (int i = 0; i < 4; ++i)
            #pragma unroll
            for (int j = 0; j < 4; ++j)
                acc[i][j] = __builtin_amdgcn_mfma_f32_16x16x32_bf16(a[i], b[j], acc[i][j], 0, 0, 0);
        __syncthreads();
    }

    // epilogue: C/D col = lane&15, row = (lane>>4)*4 + reg   [m89/m91]
    const int cn = lane & 15, rb = (lane >> 4) * 4;
    const int cg   = (n0 + wn) >> 6;      // wave-uniform 64-col group
    const int type = cg % 3;              // 0=q, 1=k, 2=v
    const int hb   = cg / 3;
    u16* dst = (type == 0) ? Qb : (type == 1) ? Kb : Vb;
    const bool sg = (type < 2);
    float col4[4];
    #pragma unroll
    for (int j = 0; j < 4; ++j) {
        int ccol = j * 16 + cn;
        float bv = bias[n0 + wn + ccol];
        int outcol = hb * 64 + ccol;
        float csum = 0.f;
        #pragma unroll
        for (int i = 0; i < 4; ++i) {
            int mbase = m0 + wm + i * 16 + rb;
            f32x4 av = acc[i][j];
            #pragma unroll
            for (int r = 0; r < 4; ++r) {
                float v = av[r] + bv;
                if (sg) v = 1.f / (1.f + __expf(-v));
                csum += v;
                dst[(size_t)(mbase + r) * 512 + outcol] = f2bf(v);
            }
        }
        csum += __shfl_xor(csum, 16);     // reduce 4 row-quads -> 64-row sum
        csum += __shfl_xor(csum, 32);
        col4[j] = csum;
    }
    if (lane < 16) {
        #pragma unroll
        for (int j = 0; j < 4; ++j)
            csums[wave >> 1][wave & 1][j * 16 + lane] = col4[j];
    }
    __syncthreads();
    if (tid < 128) {                      // 128-row col sums -> global partials
        int half = tid >> 6, c6 = tid & 63;
        float s = csums[half][0][c6] + csums[half][1][c6];
        int cgb = blockIdx.x * 2 + half;  // global col64 group 0..23
        pgem[((size_t)cgb * 128 + blockIdx.y) * 64 + c6] = s;
    }
}

// fold GEMM column partials over the 32 m-tiles of each batch -> sumq/sumk
// grid 8 = 2 types x 4 b, 256 threads
__global__ __launch_bounds__(256) void fold_gemm(
        const float* __restrict__ pgem, float* __restrict__ sumq, float* __restrict__ sumk) {
    int type = blockIdx.x >> 2, b = blockIdx.x & 3;
    float* dst = (type == 0) ? sumq : sumk;
    #pragma unroll
    for (int rep = 0; rep < 2; ++rep) {
        int col = rep * 256 + threadIdx.x;      // 0..511
        int hbq = col >> 6, c6 = col & 63;
        int cg = hbq * 3 + type;
        float a = 0.f;
        for (int mt = 0; mt < 32; ++mt)
            a += pgem[((size_t)cg * 128 + b * 32 + mt) * 64 + c6];
        dst[b * 512 + col] = a;
    }
}

// ---------------- GEMM2: out = r @ Wout^T + b (fp32 out) ----------------
__global__ __launch_bounds__(256) void gemm_out(
        const u16* __restrict__ A, const u16* __restrict__ Bw,
        const float* __restrict__ bias, float* __restrict__ C,
        int N, int K) {
    __shared__ u16 As[128 * 32];
    __shared__ u16 Bs[128 * 32];
    const int tid  = threadIdx.x;
    const int wave = tid >> 6, lane = tid & 63;
    const int m0 = blockIdx.y * 128, n0 = blockIdx.x * 128;
    const int wm = (wave & 1) * 64, wn = (wave >> 1) * 64;
    const int srow = wave * 16 + (lane >> 2);
    const int scol = (((lane & 3) ^ ((lane >> 2) & 3))) * 8;
    const u16* Ap = A  + (size_t)(m0 + srow) * K + scol;
    const u16* Bp = Bw + (size_t)(n0 + srow) * K + scol;
    u16* AsW = &As[wave * 512];
    u16* BsW = &Bs[wave * 512];
    const size_t rstep = (size_t)64 * K;
    f32x4 acc[4][4] = {};
    const int fr = lane & 15, fq = lane >> 4;
    const int fkA = ((fq ^ (fr & 3))) * 8;
    for (int k0 = 0; k0 < K; k0 += 32) {
        async16(Ap + k0,         AsW);
        async16(Ap + k0 + rstep, AsW + 2048);
        async16(Bp + k0,         BsW);
        async16(Bp + k0 + rstep, BsW + 2048);
        __syncthreads();
        bf16x8 a[4], b[4];
        #pragma unroll
        for (int i = 0; i < 4; ++i)
            a[i] = *(const bf16x8*)&As[(wm + i * 16 + fr) * 32 + fkA];
        #pragma unroll
        for (int j = 0; j < 4; ++j)
            b[j] = *(const bf16x8*)&Bs[(wn + j * 16 + fr) * 32 + fkA];
        #pragma unroll
        for (int i = 0; i < 4; ++i)
            #pragma unroll
            for (int j = 0; j < 4; ++j)
                acc[i][j] = __builtin_amdgcn_mfma_f32_16x16x32_bf16(a[i], b[j], acc[i][j], 0, 0, 0);
        __syncthreads();
    }
    const int cn = lane & 15, rb = (lane >> 4) * 4;
    #pragma unroll
    for (int i = 0; i < 4; ++i) {
        int mbase = m0 + wm + i * 16 + rb;
        #pragma unroll
        for (int j = 0; j < 4; ++j) {
            int nn = n0 + wn + j * 16 + cn;
            float bv = bias[nn];
            f32x4 av = acc[i][j];
            #pragma unroll
            for (int r = 0; r < 4; ++r)
                C[(size_t)(mbase + r) * N + nn] = av[r] + bv;
        }
    }
}

// ---------------- P2: i,o dots + partial sums of q/i, k/o  (grid 2048 x 256) ----------------
// Block covers 8 positions (2 per wave). Partials: part[b*512+chunk][1024].
__global__ __launch_bounds__(256, 4) void p2_io(
        const u16* __restrict__ Qg, const u16* __restrict__ Kg,
        const float* __restrict__ sumq, const float* __restrict__ sumk,
        float* __restrict__ iv, float* __restrict__ part) {
    __shared__ float red[4][1024];
    const int blk = blockIdx.x;
    const int b = blk >> 9, chunk = blk & 511;
    const int w = threadIdx.x >> 6, lane = threadIdx.x & 63;
    const int p0 = b * S_ + chunk * 8 + w * 2;
    float skL[8], sqL[8];
    #pragma unroll
    for (int j = 0; j < 8; ++j) {
        skL[j] = sumk[b * 512 + lane * 8 + j];
        sqL[j] = sumq[b * 512 + lane * 8 + j];
    }
    float aqi[8] = {}, ako[8] = {};
    #pragma unroll
    for (int it = 0; it < 2; ++it) {
        int p = p0 + it;
        size_t off = (size_t)p * 512 + lane * 8;
        u16x8 q8 = *(const u16x8*)(Qg + off);
        u16x8 k8 = *(const u16x8*)(Kg + off);
        float qf[8], kf[8];
        #pragma unroll
        for (int j = 0; j < 8; ++j) { qf[j] = bf2f(q8[j]); kf[j] = bf2f(k8[j]); }
        float di = 0.f, dox = 0.f;
        #pragma unroll
        for (int j = 0; j < 8; ++j) { di += qf[j] * skL[j]; dox += kf[j] * sqL[j]; }
        di  += __shfl_xor(di, 1);  di  += __shfl_xor(di, 2);  di  += __shfl_xor(di, 4);
        dox += __shfl_xor(dox, 1); dox += __shfl_xor(dox, 2); dox += __shfl_xor(dox, 4);
        if ((lane & 7) == 0) iv[(size_t)p * 8 + (lane >> 3)] = di;
        float ri = rcpf(di), ro = rcpf(dox);
        #pragma unroll
        for (int j = 0; j < 8; ++j) { aqi[j] += qf[j] * ri; ako[j] += kf[j] * ro; }
    }
    #pragma unroll
    for (int j = 0; j < 8; ++j) {
        red[w][lane * 8 + j]       = aqi[j];
        red[w][512 + lane * 8 + j] = ako[j];
    }
    __syncthreads();
    const int tid = threadIdx.x;
    float* dst = part + (size_t)blk * 1024;
    #pragma unroll
    for (int rr = 0; rr < 4; ++rr) {
        int slot = rr * 256 + tid;
        dst[slot] = red[0][slot] + red[1][slot] + red[2][slot] + red[3][slot];
    }
}

// fold 512 chunk partials -> sumqi/sumko  (grid 64 x 256, fully coalesced)
__global__ __launch_bounds__(256) void fold_io(
        const float* __restrict__ part, float* __restrict__ sumqi, float* __restrict__ sumko) {
    __shared__ float red[4][64];
    const int b = blockIdx.x >> 4, sgrp = blockIdx.x & 15;
    const int sub = threadIdx.x >> 6, lane = threadIdx.x & 63;
    float a = 0.f;
    for (int i = 0; i < 128; ++i) {
        int c = sub + i * 4;
        a += part[((size_t)(b * 512 + c)) * 1024 + sgrp * 64 + lane];
    }
    red[sub][lane] = a;
    __syncthreads();
    if (threadIdx.x < 64) {
        float s = red[0][lane] + red[1][lane] + red[2][lane] + red[3][lane];
        int slot = sgrp * 64 + lane;
        if (slot < 512) sumqi[b * 512 + slot] = s;
        else            sumko[b * 512 + (slot - 512)] = s;
    }
}

// ---------------- P3: o_hat -> wexp, sm partials (reads K only)  (grid 2048 x 256) ----------------
__global__ __launch_bounds__(256, 4) void p3_ohat(
        const u16* __restrict__ Kg, const float* __restrict__ sumqi,
        float* __restrict__ wexp, float* __restrict__ smpart) {
    __shared__ float smr[4][8];
    const int blk = blockIdx.x;
    const int b = blk >> 9, chunk = blk & 511;
    const int w = threadIdx.x >> 6, lane = threadIdx.x & 63;
    const int p0 = b * S_ + chunk * 8 + w * 2;
    float sqiL[8];
    #pragma unroll
    for (int j = 0; j < 8; ++j) sqiL[j] = sumqi[b * 512 + lane * 8 + j];
    float smacc = 0.f;
    #pragma unroll
    for (int it = 0; it < 2; ++it) {
        int p = p0 + it;
        u16x8 k8 = *(const u16x8*)(Kg + (size_t)p * 512 + lane * 8);
        float doh = 0.f;
        #pragma unroll
        for (int j = 0; j < 8; ++j) doh += bf2f(k8[j]) * sqiL[j];
        doh += __shfl_xor(doh, 1); doh += __shfl_xor(doh, 2); doh += __shfl_xor(doh, 4);
        if ((lane & 7) == 0) {
            float we = __expf(fminf(doh, 80.f));   // o_hat ~ O(1); no max-sub needed
            wexp[(size_t)p * 8 + (lane >> 3)] = we;
            smacc += we;
        }
    }
    if ((lane & 7) == 0) smr[w][lane >> 3] = smacc;
    __syncthreads();
    if (threadIdx.x < 8)
        smpart[(size_t)blk * 8 + threadIdx.x] =
            smr[0][threadIdx.x] + smr[1][threadIdx.x] + smr[2][threadIdx.x] + smr[3][threadIdx.x];
}

// fold sm partials  (grid 32 x 256): block per (b,h)
__global__ __launch_bounds__(256) void fold_sm(const float* __restrict__ smpart, float* __restrict__ sm) {
    __shared__ float red[256];
    int bh = blockIdx.x;
    int b = bh >> 3, h = bh & 7;
    float a = 0.f;
    for (int c = threadIdx.x; c < 512; c += 256)
        a += smpart[((size_t)b * 512 + c) * 8 + h];
    red[threadIdx.x] = a;
    __syncthreads();
    for (int st = 128; st > 0; st >>= 1) {
        if (threadIdx.x < st) red[threadIdx.x] += red[threadIdx.x + st];
        __syncthreads();
    }
    if (threadIdx.x == 0) sm[bh] = red[0];
}

// ---------------- P4: finalize, now also computes i_hat in-register ----------------
// grid 2048 x 256; 2 positions per wave.
__global__ __launch_bounds__(256) void finalize_kernel(
        const u16* __restrict__ Qg, const u16* __restrict__ Kg, const u16* __restrict__ Vg,
        const float* __restrict__ sumko, const float* __restrict__ iv,
        const float* __restrict__ wexp, const float* __restrict__ sm,
        u16* __restrict__ Rg) {
    __shared__ float Ml[4][2][8][9];
    __shared__ float vw[4][2][8][68];
    const int w = threadIdx.x >> 6, lane = threadIdx.x & 63;
    const int pp = blockIdx.x * 8 + w * 2;
    const int b = pp >> 12;

    const int pl = (lane >> 3) & 1, hh = lane & 7, quad = lane >> 4;
    const u16* qa = Qg + (size_t)(pp + pl) * 512 + hh * 64 + quad * 8;
    const u16* ka = Kg + (size_t)(pp + pl) * 512 + hh * 64 + quad * 8;
    u16x8 qv0 = *(const u16x8*)qa;
    u16x8 qv1 = *(const u16x8*)(qa + 32);
    bf16x8 b0 = __builtin_bit_cast(bf16x8, *(const u16x8*)ka);
    bf16x8 b1 = __builtin_bit_cast(bf16x8, *(const u16x8*)(ka + 32));
    f32x4 accm = {0.f, 0.f, 0.f, 0.f};
    accm = __builtin_amdgcn_mfma_f32_16x16x32_bf16(__builtin_bit_cast(bf16x8, qv0), b0, accm, 0, 0, 0);
    accm = __builtin_amdgcn_mfma_f32_16x16x32_bf16(__builtin_bit_cast(bf16x8, qv1), b1, accm, 0, 0, 0);

    // i_hat = <q, sumko> for (pp+pl, hh): lane partial over its 16 d's, then
    // quad-reduce (xor 16,32) -> every lane holds its (pl,hh)'s dih.
    const float* sko = sumko + b * 512 + hh * 64 + quad * 8;
    float dp = 0.f;
    #pragma unroll
    for (int j = 0; j < 8; ++j)
        dp += bf2f(qv0[j]) * sko[j] + bf2f(qv1[j]) * sko[32 + j];
    dp += __shfl_xor(dp, 16);
    dp += __shfl_xor(dp, 32);
    float sig = 1.f / (1.f + __expf(-dp));
    float myrsc = sig * rcpf(iv[(size_t)(pp + pl) * 8 + hh]);

    // C: row=(lane>>4)*4+r, col=lane&15.  Diagonal p-quadrants only.
    const int plm = lane >> 5, hr = ((lane >> 4) & 1) * 4, h2c = lane & 7;
    float rsc4[4];
    #pragma unroll
    for (int r = 0; r < 4; ++r)
        rsc4[r] = __shfl(myrsc, plm * 8 + hr + r);   // rsc of (pp+plm, hr+r)
    if (((lane >> 5) & 1) == ((lane >> 3) & 1)) {
        #pragma unroll
        for (int r = 0; r < 4; ++r)
            Ml[w][plm][hr + r][h2c] = accm[r] * rsc4[r];
    }
    // vw = v * softmax-weight (fp32, LDS)
    {
        int hv = lane >> 3, e0 = (lane & 7) * 8;
        float invsm = rcpf(sm[b * 8 + hv]);
        #pragma unroll
        for (int plv = 0; plv < 2; ++plv) {
            u16x8 v8 = *(const u16x8*)(Vg + (size_t)(pp + plv) * 512 + lane * 8);
            float wgt = wexp[(size_t)(pp + plv) * 8 + hv] * invsm;
            f32x4 x0, x1;
            #pragma unroll
            for (int j = 0; j < 4; ++j) { x0[j] = bf2f(v8[j]) * wgt; x1[j] = bf2f(v8[4 + j]) * wgt; }
            *(f32x4*)&vw[w][plv][hv][e0]     = x0;
            *(f32x4*)&vw[w][plv][hv][e0 + 4] = x1;
        }
    }
    __syncthreads();
    // PV: lane covers (p_l = lane>>5, h = (lane&31)>>2, 16-elem e-chunk)
    {
        int plo = lane >> 5, idx = lane & 31, h = idx >> 2, eq = (idx & 3) * 16;
        float outv[16] = {};
        #pragma unroll
        for (int h2 = 0; h2 < 8; ++h2) {
            float m = Ml[w][plo][h][h2];
            #pragma unroll
            for (int c = 0; c < 4; ++c) {
                f32x4 vv = *(const f32x4*)&vw[w][plo][h2][eq + c * 4];
                #pragma unroll
                for (int j = 0; j < 4; ++j) outv[c * 4 + j] += m * vv[j];
            }
        }
        u16x8 o0, o1;
        #pragma unroll
        for (int j = 0; j < 8; ++j) { o0[j] = f2bf(outv[j]); o1[j] = f2bf(outv[8 + j]); }
        u16* dstp = Rg + (size_t)(pp + plo) * 512 + h * 64 + eq;
        *(u16x8*)dstp       = o0;
        *(u16x8*)(dstp + 8) = o1;
    }
}

// ---------------- launch ----------------
extern "C" void kernel_launch(void* const* d_in, const int* in_sizes, int n_in,
                              void* d_out, int out_size, void* d_ws, size_t ws_size,
                              hipStream_t stream) {
    const float* x    = (const float*)d_in[0];
    const float* Wqkv = (const float*)d_in[1];
    const float* bqkv = (const float*)d_in[2];
    const float* Wout = (const float*)d_in[3];
    const float* bout = (const float*)d_in[4];
    float* out = (float*)d_out;
    char* ws = (char*)d_ws;

    constexpr size_t SZ_XBF  = (size_t)NPOS * E_ * 2;     // 16 MB (reused for r)
    constexpr size_t SZ_WQBF = (size_t)QKVC * E_ * 2;
    constexpr size_t SZ_WOBF = (size_t)E_ * E_ * 2;
    constexpr size_t SZ_QKVB = (size_t)NPOS * E_ * 2;     // 16 MB each of Q,K,V
    constexpr size_t SZ_SUM  = (size_t)B_ * 512 * 4;      // 8 KB each
    constexpr size_t SZ_V8   = (size_t)NPOS * 8 * 4;      // 512 KB each
    constexpr size_t SZ_PGEM = (size_t)24 * 128 * 64 * 4; // 786 KB
    constexpr size_t SZ_PART = (size_t)2048 * 1024 * 4;   // 8 MB

    size_t off = 0;
    u16*   xbf    = (u16*)(ws + off);   off += SZ_XBF;
    u16*   wqbf   = (u16*)(ws + off);   off += SZ_WQBF;
    u16*   wobf   = (u16*)(ws + off);   off += SZ_WOBF;
    u16*   Qb     = (u16*)(ws + off);   off += SZ_QKVB;
    u16*   Kb     = (u16*)(ws + off);   off += SZ_QKVB;
    u16*   Vb     = (u16*)(ws + off);   off += SZ_QKVB;
    float* sumq   = (float*)(ws + off); off += SZ_SUM;
    float* sumk   = (float*)(ws + off); off += SZ_SUM;
    float* sumqi  = (float*)(ws + off); off += SZ_SUM;
    float* sumko  = (float*)(ws + off); off += SZ_SUM;
    float* sm     = (float*)(ws + off); off += 256;
    float* iv     = (float*)(ws + off); off += SZ_V8;
    float* wexp   = (float*)(ws + off); off += SZ_V8;
    float* smpart = (float*)(ws + off); off += (size_t)2048 * 8 * 4;
    float* pgem   = (float*)(ws + off); off += SZ_PGEM;
    float* part   = (float*)(ws + off); off += SZ_PART;
    u16*   rbf    = xbf;   // reuse after GEMM1

    // 1) conversions
    {
        const int n4 = (NPOS * E_ + QKVC * E_ + E_ * E_) / 4;
        cvt3<<<(n4 + 255) / 256, 256, 0, stream>>>(
            (const float4*)x, (const float4*)Wqkv, (const float4*)Wout,
            (u16x4*)xbf, (u16x4*)wqbf, (u16x4*)wobf);
    }

    // 2) GEMM1 (sigmoid + de-interleave + column-sum partials)
    gemm_qkv<<<dim3(QKVC / 128, NPOS / 128), 256, 0, stream>>>(
        xbf, wqbf, bqkv, Qb, Kb, Vb, pgem, K_);
    fold_gemm<<<8, 256, 0, stream>>>(pgem, sumq, sumk);

    // 3) i,o + partial sums of q/i, k/o
    p2_io<<<2048, 256, 0, stream>>>(Qb, Kb, sumq, sumk, iv, part);
    fold_io<<<64, 256, 0, stream>>>(part, sumqi, sumko);

    // 4) o_hat -> wexp, sm partials (K only)
    p3_ohat<<<2048, 256, 0, stream>>>(Kb, sumqi, wexp, smpart);
    fold_sm<<<32, 256, 0, stream>>>(smpart, sm);

    // 5) finalize (computes i_hat in-register) -> r (bf16)
    finalize_kernel<<<2048, 256, 0, stream>>>(Qb, Kb, Vb, sumko, iv, wexp, sm, rbf);

    // 6) GEMM2
    gemm_out<<<dim3(E_ / 128, NPOS / 128), 256, 0, stream>>>(
        rbf, wobf, bout, out, E_, K_);
}